// Round 6
// baseline (329.321 us; speedup 1.0000x reference)
//
#include <hip/hip_runtime.h>

// x: (16, 3, 512, 512) f32 -> out: (16, 15, 512, 512) f32
// Round 6: OUTPUT-LINEAR PERSISTENT SWEEP.
// R4 proved traffic is byte-ideal (WRITE=240MiB, FETCH=40MB) at only 2.9 TB/s;
// R5 proved per-wave contiguity is not the lever. New theory: fill/copy reach
// ~80% peak because grid-stride keeps the in-flight address window compact
// (~tens of MB, sweeping linearly) -> DRAM row-buffer hits. Our previous
// kernels sprayed 5 plane-streams per block over the whole 1.2GB output.
// This version: work unit = one 4KB output row-pair in ONE plane, units
// ordered by output address, processed grid-stride by exactly-resident waves
// (1536 blocks x 4 waves = 6144 waves, 61440 units, 10 units/wave, no tail).
// Redundant per-band haar recompute reads come from L3 (input = 50MB, L3-hot).
#define HF   512
#define WF   512
#define HH   256
#define HW   (HF * WF)
#define NPLANES 240                 // 48 bc * 5 bands (plane idx = bc*5+band)
#define NUNITS  (NPLANES * HH)      // 61440 row-pair units
#define NBLK    1536                // resident even at 6 waves/SIMD occupancy
#define NWAVES  (NBLK * 4)          // 6144; 61440/6144 = 10 units per wave exact

typedef float v4 __attribute__((ext_vector_type(4)));
typedef float v2 __attribute__((ext_vector_type(2)));

__device__ __forceinline__ v4 haar2(float a, float b, float c, float d) {
    const float s1 = a + b, d1 = a - b, s2 = c + d, d2 = c - d;
    v4 v;
    v.x = (s1 + s2) * 0.5f;   // LL
    v.y = (s1 - s2) * 0.5f;   // LH
    v.z = (d1 + d2) * 0.5f;   // HL
    v.w = (d1 - d2) * 0.5f;   // HH
    return v;
}

// One 4-output-col unit: coef cols j-1..j+2, out cols x0..x0+3 (x0 = 2j).
// Produces even-row (ve) and odd-row (vo) bilinear values for all 4 bands.
__device__ __forceinline__ void unit_compute(const float* __restrict__ p0,
                                             const float* __restrict__ p1,
                                             const float* __restrict__ p2,
                                             int x0, int xl, int xr,
                                             v4 (&ve)[4], v4 (&vo)[4]) {
    {   // coef row k-1
        const v2 lt = *reinterpret_cast<const v2*>(p0 + xl);
        const v2 lb = *reinterpret_cast<const v2*>(p0 + WF + xl);
        const v4 t  = *reinterpret_cast<const v4*>(p0 + x0);
        const v4 u  = *reinterpret_cast<const v4*>(p0 + WF + x0);
        const v2 rt = *reinterpret_cast<const v2*>(p0 + xr);
        const v2 rb = *reinterpret_cast<const v2*>(p0 + WF + xr);
        const v4 A = haar2(lt.x, lt.y, lb.x, lb.y);
        const v4 B = haar2(t.x,  t.y,  u.x,  u.y);
        const v4 C = haar2(t.z,  t.w,  u.z,  u.w);
        const v4 D = haar2(rt.x, rt.y, rb.x, rb.y);
        ve[0] = (A * 0.25f + B * 0.75f) * 0.25f;
        ve[1] = (B * 0.75f + C * 0.25f) * 0.25f;
        ve[2] = (B * 0.25f + C * 0.75f) * 0.25f;
        ve[3] = (C * 0.75f + D * 0.25f) * 0.25f;
    }
    {   // coef row k
        const v2 lt = *reinterpret_cast<const v2*>(p1 + xl);
        const v2 lb = *reinterpret_cast<const v2*>(p1 + WF + xl);
        const v4 t  = *reinterpret_cast<const v4*>(p1 + x0);
        const v4 u  = *reinterpret_cast<const v4*>(p1 + WF + x0);
        const v2 rt = *reinterpret_cast<const v2*>(p1 + xr);
        const v2 rb = *reinterpret_cast<const v2*>(p1 + WF + xr);
        const v4 A = haar2(lt.x, lt.y, lb.x, lb.y);
        const v4 B = haar2(t.x,  t.y,  u.x,  u.y);
        const v4 C = haar2(t.z,  t.w,  u.z,  u.w);
        const v4 D = haar2(rt.x, rt.y, rb.x, rb.y);
        v4 h;
        h = A * 0.25f + B * 0.75f;  ve[0] += h * 0.75f;  vo[0] = h * 0.75f;
        h = B * 0.75f + C * 0.25f;  ve[1] += h * 0.75f;  vo[1] = h * 0.75f;
        h = B * 0.25f + C * 0.75f;  ve[2] += h * 0.75f;  vo[2] = h * 0.75f;
        h = C * 0.75f + D * 0.25f;  ve[3] += h * 0.75f;  vo[3] = h * 0.75f;
    }
    {   // coef row k+1
        const v2 lt = *reinterpret_cast<const v2*>(p2 + xl);
        const v2 lb = *reinterpret_cast<const v2*>(p2 + WF + xl);
        const v4 t  = *reinterpret_cast<const v4*>(p2 + x0);
        const v4 u  = *reinterpret_cast<const v4*>(p2 + WF + x0);
        const v2 rt = *reinterpret_cast<const v2*>(p2 + xr);
        const v2 rb = *reinterpret_cast<const v2*>(p2 + WF + xr);
        const v4 A = haar2(lt.x, lt.y, lb.x, lb.y);
        const v4 B = haar2(t.x,  t.y,  u.x,  u.y);
        const v4 C = haar2(t.z,  t.w,  u.z,  u.w);
        const v4 D = haar2(rt.x, rt.y, rb.x, rb.y);
        vo[0] += (A * 0.25f + B * 0.75f) * 0.25f;
        vo[1] += (B * 0.75f + C * 0.25f) * 0.25f;
        vo[2] += (B * 0.25f + C * 0.75f) * 0.25f;
        vo[3] += (C * 0.75f + D * 0.25f) * 0.25f;
    }
}

__global__ __launch_bounds__(256) void wavelet_kernel(const float* __restrict__ x,
                                                      float* __restrict__ out) {
    const int tx  = threadIdx.x;                       // 0..63
    const int wid = blockIdx.x * 4 + threadIdx.y;      // global wave id 0..NWAVES-1

    // column geometry (same for every unit)
    const int xA  = 4 * tx;                            // left half-row, out cols xA..xA+3
    const int xlA = (tx == 0) ? 0 : xA - 2;
    const int xrA = xA + 4;                            // <=256, never clamps
    const int xB  = 256 + 4 * tx;                      // right half-row
    const int xlB = xB - 2;                            // >=254, never clamps
    const int xrB = (tx == 63) ? (WF - 2) : (xB + 4);

    for (int u = wid; u < NUNITS; u += NWAVES) {
        const int plane = u >> 8;                      // 0..239 (= bc*5 + band)
        const int k     = u & (HH - 1);                // coef row 0..255
        const int bc    = plane / 5;
        const int band  = plane - bc * 5;

        const float* __restrict__ xin = x + (size_t)bc * HW;
        float* __restrict__ orow = out + (size_t)plane * HW + (size_t)(2 * k) * WF;

        if (band == 0) {
            // identity copy of input rows 2k, 2k+1 (4KB contiguous)
            const float* p = xin + (size_t)(2 * k) * WF;
            const v4 a0 = *reinterpret_cast<const v4*>(p + xA);
            const v4 b0 = *reinterpret_cast<const v4*>(p + xB);
            const v4 a1 = *reinterpret_cast<const v4*>(p + WF + xA);
            const v4 b1 = *reinterpret_cast<const v4*>(p + WF + xB);
            __builtin_nontemporal_store(a0, reinterpret_cast<v4*>(orow + xA));
            __builtin_nontemporal_store(b0, reinterpret_cast<v4*>(orow + xB));
            __builtin_nontemporal_store(a1, reinterpret_cast<v4*>(orow + WF + xA));
            __builtin_nontemporal_store(b1, reinterpret_cast<v4*>(orow + WF + xB));
        } else {
            const int ku = (k == 0) ? 0 : k - 1;
            const int kd = (k == HH - 1) ? HH - 1 : k + 1;
            const float* p0 = xin + (size_t)(2 * ku) * WF;
            const float* p1 = xin + (size_t)(2 * k)  * WF;
            const float* p2 = xin + (size_t)(2 * kd) * WF;

            v4 ve[4], vo[4];

#define EXTRACT_STORE(COMP, XOFF)                                                      \
            {                                                                          \
                v4 e, o;                                                               \
                e.x = ve[0].COMP; e.y = ve[1].COMP; e.z = ve[2].COMP; e.w = ve[3].COMP;\
                o.x = vo[0].COMP; o.y = vo[1].COMP; o.z = vo[2].COMP; o.w = vo[3].COMP;\
                __builtin_nontemporal_store(e, reinterpret_cast<v4*>(orow + (XOFF)));  \
                __builtin_nontemporal_store(o, reinterpret_cast<v4*>(orow + WF + (XOFF)));\
            }
#define DO_UNIT(X0, XL, XR)                                                            \
            unit_compute(p0, p1, p2, (X0), (XL), (XR), ve, vo);                        \
            switch (band) {                                                            \
                case 1: EXTRACT_STORE(x, X0) break;                                    \
                case 2: EXTRACT_STORE(y, X0) break;                                    \
                case 3: EXTRACT_STORE(z, X0) break;                                    \
                default: EXTRACT_STORE(w, X0) break;                                   \
            }

            DO_UNIT(xA, xlA, xrA)   // left half-row
            DO_UNIT(xB, xlB, xrB)   // right half-row
#undef DO_UNIT
#undef EXTRACT_STORE
        }
    }
}

extern "C" void kernel_launch(void* const* d_in, const int* in_sizes, int n_in,
                              void* d_out, int out_size, void* d_ws, size_t ws_size,
                              hipStream_t stream) {
    const float* x = (const float*)d_in[0];
    float* out = (float*)d_out;
    dim3 grid(NBLK);               // 1536 blocks -> 6144 waves, all resident
    dim3 block(64, 4);
    hipLaunchKernelGGL(wavelet_kernel, grid, block, 0, stream, x, out);
}